// Round 3
// baseline (69.926 us; speedup 1.0000x reference)
//
#include <hip/hip_runtime.h>
#include <math.h>

// ContactModel, overlapping-wave version, round-1 numerics.
// Wave w computes sphere positions for batches [63w, 63w+63] (lane i -> 63w+i);
// lanes 1..63 write outputs using lane i-1's positions via __shfl_up as the
// previous-batch position (bitwise identical to recomputing them). Wave 0
// lane 0 writes batch 0 with shfl_up-self => vel exactly 0 (reference
// semantics). All transcendentals/divisions are libm-precise (round-1 proven).

__global__ __launch_bounds__(256)
void contact_kernel(const float* __restrict__ joints,
                    const float* __restrict__ jori,
                    float* __restrict__ out, const int B)
{
    const int lane = threadIdx.x & 63;
    const int wg   = blockIdx.x * 4 + (threadIdx.x >> 6);   // global wave id
    const long bL  = (long)wg * 63 + lane;
    const bool do_write = (bL < B) && (lane > 0 || bL == 0);
    const int  b = (bL < (long)B) ? (int)bL : (B - 1);      // clamped for loads

    float px[12], py[12], pz[12];
    float fx[12], fy[12], fz[12];   // velocity first, then force in-place

    // ---- positions for own batch (bodies 4,5,9,10 only) ----
    {
        const float c_lx[12] = {0.00190115788407966f, 0.148386399942063f, 0.133001170607051f,
                                0.0662346661991635f, 0.06f, 0.045f,
                                0.00190115788407966f, 0.148386399942063f, 0.133001170607051f,
                                0.0662346661991635f, 0.06f, 0.045f};
        const float c_lz[12] = {-0.00382630379623308f, -0.028713422052654f, 0.0516362473449566f,
                                 0.0263641606741698f, -0.0187603084619177f, 0.0618569567549652f,
                                 0.00382630379623308f, 0.028713422052654f, -0.0516362473449566f,
                                -0.0263641606741698f, 0.0187603084619177f, -0.0618569567549652f};
        const float ly = -0.01f;
        const int bodies[4] = {4, 5, 9, 10};
        const int sbeg[4]   = {0, 4, 6, 10};
        const int scnt[4]   = {4, 2, 4, 2};
        const float* jr = joints + (size_t)b * 72;
        const float* mr = jori   + (size_t)b * 216;
        #pragma unroll
        for (int bi = 0; bi < 4; ++bi) {
            const int body = bodies[bi];
            const float jx = jr[body*3+0], jy = jr[body*3+1], jz = jr[body*3+2];
            const float* m = mr + body*9;
            const float m00=m[0],m01=m[1],m02=m[2];
            const float m10=m[3],m11=m[4],m12=m[5];
            const float m20=m[6],m21=m[7],m22=m[8];
            #pragma unroll
            for (int si = 0; si < 4; ++si) {
                if (si < scnt[bi]) {
                    const int s = sbeg[bi] + si;
                    const float lx = c_lx[s], lz = c_lz[s];
                    px[s] = jx + m00*lx + m01*ly + m02*lz;
                    py[s] = jy + m10*lx + m11*ly + m12*lz;
                    pz[s] = jz + m20*lx + m21*ly + m22*lz;
                }
            }
        }
    }

    // ---- velocity from neighbor lane (prev batch) ----
    #pragma unroll
    for (int s = 0; s < 12; ++s) {
        fx[s] = (px[s] - __shfl_up(px[s], 1)) * 20.0f;   // 1/DT = 20
        fy[s] = (py[s] - __shfl_up(py[s], 1)) * 20.0f;
        fz[s] = (pz[s] - __shfl_up(pz[s], 1)) * 20.0f;
    }

    // ---- contact forces (round-1 numerics, in-place over velocity) ----
    const float KF  = 1077.21734501594f;                 // 0.5 * 100000**(2/3)
    const float CFH = (4.0f/3.0f) * KF * sqrtf(0.032f * KF);
    #pragma unroll
    for (int s = 0; s < 12; ++s) {
        const float vx = fx[s], vy = fy[s], vz = fz[s];
        const float ind     = -py[s];                    // GROUND_HEIGHT = 0
        const float ind_vel = -vy;
        const float q   = ind*ind + 1e-5f;
        const float fH  = CFH * sqrtf(q * sqrtf(q));     // q^0.75
        const float fHd = fH * (1.0f + 0.3f * ind_vel);  // 1.5*DISSIPATION = 0.3
        const float t1 = (0.5f*tanhf(50.0f*(ind_vel + 3.3333333333333335f)) + 0.5f) + 1e-16f;
        const float t2 = (0.5f*tanhf(300.0f*ind) + 0.5f) + 1e-16f;
        const float fn = t1 * t2 * fHd;
        const float vslip = sqrtf(vx*vx + vz*vz + 1e-5f);
        const float vrel  = vslip * 5.0f;                // / TRANSITION_VELOCITY
        // STATIC==DYNAMIC==0.8 -> 2*(S-D)/(1+vrel^2) term is exactly 0
        const float mu  = fminf(vrel, 1.0f) * 0.8f + 0.5f * vslip;
        const float ffr = fn * mu;
        const float sc  = ffr / (vslip + 1e-5f);
        fx[s] = -sc * vx;
        fy[s] = fn;
        fz[s] = -sc * vz;
    }

    // ---- group reductions: g=0 all, g=1 right(0..6), g=2 left(6..12) ----
    float res[3][9];
    const int gs0[3] = {0, 0, 6};
    const int gs1[3] = {12, 6, 12};
    #pragma unroll
    for (int g = 0; g < 3; ++g) {
        float Fx=0.f, Fy=0.f, Fz=0.f, tw=0.f, sx=0.f, sz=0.f;
        #pragma unroll
        for (int s = 0; s < 12; ++s) {
            if (s >= gs0[g] && s < gs1[g]) {
                Fx += fx[s]; Fy += fy[s]; Fz += fz[s];
                const float w = fy[s] > 0.f ? fy[s] : 0.f;
                tw += w;
                sx += px[s] * w;
                sz += pz[s] * w;
            }
        }
        const bool has = tw > 0.f;
        const float cx = has ? sx / tw : 0.f;
        const float cz = has ? sz / tw : 0.f;
        float Tx=0.f, Ty=0.f, Tz=0.f;
        #pragma unroll
        for (int s = 0; s < 12; ++s) {
            if (s >= gs0[g] && s < gs1[g]) {
                if (fy[s] > 0.f) {
                    const float rx = px[s]-cx, ry = py[s], rz = pz[s]-cz;  // cy==0
                    Tx += ry*fz[s] - rz*fy[s];
                    Ty += rz*fx[s] - rx*fz[s];
                    Tz += rx*fy[s] - ry*fx[s];
                }
            }
        }
        res[g][0]=Fx; res[g][1]=Fy; res[g][2]=Fz;
        res[g][3]=Tx; res[g][4]=Ty; res[g][5]=Tz;
        res[g][6]=cx; res[g][7]=0.f; res[g][8]=cz;
    }

    // ---- stores ----
    if (do_write) {
        const size_t sB = (size_t)B;
        const size_t t3 = (size_t)b * 3;
        float* o;
        o = out;           o[t3]=res[0][0]; o[t3+1]=res[0][1]; o[t3+2]=res[0][2];
        o = out + sB*3;    o[t3]=res[0][3]; o[t3+1]=res[0][4]; o[t3+2]=res[0][5];
        o = out + sB*6;    o[t3]=res[0][6]; o[t3+1]=res[0][7]; o[t3+2]=res[0][8];
        o = out + sB*81;   o[t3]=res[1][0]; o[t3+1]=res[1][1]; o[t3+2]=res[1][2];
        o = out + sB*84;   o[t3]=res[2][0]; o[t3+1]=res[2][1]; o[t3+2]=res[2][2];
        o = out + sB*87;   o[t3]=res[1][3]; o[t3+1]=res[1][4]; o[t3+2]=res[1][5];
        o = out + sB*90;   o[t3]=res[2][3]; o[t3+1]=res[2][4]; o[t3+2]=res[2][5];
        o = out + sB*93;   o[t3]=res[1][6]; o[t3+1]=res[1][7]; o[t3+2]=res[1][8];
        o = out + sB*96;   o[t3]=res[2][6]; o[t3+1]=res[2][7]; o[t3+2]=res[2][8];

        float* osf = out + sB*9  + (size_t)b*36;
        float* opp = out + sB*45 + (size_t)b*36;
        if ((B & 3) == 0) {   // 16B alignment of both region bases and b*144
            float bufF[36], bufP[36];
            #pragma unroll
            for (int s = 0; s < 12; ++s) {
                bufF[s*3+0]=fx[s]; bufF[s*3+1]=fy[s]; bufF[s*3+2]=fz[s];
                bufP[s*3+0]=px[s]; bufP[s*3+1]=py[s]; bufP[s*3+2]=pz[s];
            }
            #pragma unroll
            for (int i = 0; i < 9; ++i) {
                reinterpret_cast<float4*>(osf)[i] = reinterpret_cast<float4*>(bufF)[i];
                reinterpret_cast<float4*>(opp)[i] = reinterpret_cast<float4*>(bufP)[i];
            }
        } else {
            #pragma unroll
            for (int s = 0; s < 12; ++s) {
                osf[s*3+0]=fx[s]; osf[s*3+1]=fy[s]; osf[s*3+2]=fz[s];
                opp[s*3+0]=px[s]; opp[s*3+1]=py[s]; opp[s*3+2]=pz[s];
            }
        }
    }
}

extern "C" void kernel_launch(void* const* d_in, const int* in_sizes, int n_in,
                              void* d_out, int out_size, void* d_ws, size_t ws_size,
                              hipStream_t stream) {
    const float* joints = (const float*)d_in[0];
    const float* jori   = (const float*)d_in[1];
    float* out = (float*)d_out;
    const int B = in_sizes[0] / 72;        // joints is (B, 24, 3)
    long waves = ((long)B + 61) / 63;      // covers batches 0..B-1 (see mapping)
    if (waves < 1) waves = 1;
    const int blocks = (int)((waves + 3) / 4);   // 4 waves per 256-thread block
    contact_kernel<<<blocks, 256, 0, stream>>>(joints, jori, out, B);
}